// Round 5
// baseline (490.623 us; speedup 1.0000x reference)
//
#include <hip/hip_runtime.h>
#include <math.h>

#define H 128
#define PC 16     // pool chunks per graph
#define GRID_BLOCKS 512   // fixed: 2 blocks/CU via __launch_bounds__, multiple of 64

#define MAGIC0 0x13572468
#define MAGIC1 0x2468ACE1

typedef _Float16 half8v __attribute__((ext_vector_type(8)));
typedef float floatx4 __attribute__((ext_vector_type(4)));

struct KParams {
  const float* x;
  const int* row;
  const int* col;
  const int* batch;
  const float* W1; const float* b1; const float* ln1w; const float* ln1b;
  const float* W2; const float* b2; const float* ln2w; const float* ln2b;
  const float* fcw; const float* fcb;
  float* out;
  int* cntE; int* offs; float* dinv; int* perm; int* esrc;
  _Float16* bufA; _Float16* bufB;
  _Float16* PW1; _Float16* PW2;
  float* slots; float* glog; int* total;
  int* bar_leaf; int* bar_root; int* bar_gen; int* bar_flag;  // ws barrier state (poisoned by harness!)
  int N; int E; int G; int CAP;
  float invM;
};

__device__ __forceinline__ int lower_bound_i(const int* a, int n, int key) {
  int lo = 0, hi = n;
  while (lo < hi) { int mid = (lo + hi) >> 1; if (a[mid] < key) lo = mid + 1; else hi = mid; }
  return lo;
}

// Software grid barrier. Requirements: gridDim.x % 64 == 0, all blocks
// co-resident (enforced: 512 blocks, __launch_bounds__(256,2) => 2 blocks/CU).
// Two-level arrival (64 leaves -> root -> generation bump); spin is a
// device-scope atomic LOAD. __threadfence() = device-scope release/acquire
// (L2 writeback/invalidate) so plain stores from phase k are visible to
// phase k+1 across XCDs. Counters self-reset; gen is monotonic (relative
// compare), so state is valid across graph replays with or without the
// harness's poison refill (init is handled by the flag protocol in main).
__device__ __forceinline__ void gridbar(int* leaf, int* root, int* gen) {
  __syncthreads();
  if (threadIdx.x == 0) {
    __threadfence();   // release: publish this block's phase writes
    int g = __hip_atomic_load(gen, __ATOMIC_RELAXED, __HIP_MEMORY_SCOPE_AGENT);
    int nb = gridDim.x;
    int li = blockIdx.x & 63;
    int lc = nb >> 6;                         // blocks per leaf
    if (atomicAdd(&leaf[li], 1) == lc - 1) {  // last in leaf
      atomicExch(&leaf[li], 0);
      __threadfence();                        // leaf reset lands before root add
      if (atomicAdd(root, 1) == 63) {         // last leaf overall
        atomicExch(root, 0);
        __threadfence();                      // root reset lands before gen bump
        atomicAdd(gen, 1);                    // release generation
      }
    }
    while (__hip_atomic_load(gen, __ATOMIC_RELAXED, __HIP_MEMORY_SCOPE_AGENT) == g)
      __builtin_amdgcn_s_sleep(2);
    __threadfence();   // acquire: invalidate local caches before next phase reads
  }
  __syncthreads();
}

// GEMM tile (fp32 input, no LN): writes O[ro] = dinv[ro] * (X@W)[ro]  (f16)
__device__ __forceinline__ void gemm_tile_f32(const float* __restrict__ Xf,
                                              const _Float16* __restrict__ PW,
                                              const float* __restrict__ dinv,
                                              _Float16* __restrict__ O,
                                              int wave, int laneid, int n) {
  int m = laneid & 15;
  int quad = laneid >> 4;
  int r0 = wave * 16;
  int row = r0 + m;
  if (row >= n) row = n - 1;
  floatx4 acc[8] = {};
  const half8v* PB8 = (const half8v*)PW;
#pragma unroll
  for (int ks = 0; ks < 4; ks++) {
    int kb = ks * 32 + quad * 8;
    const float* xr = Xf + (size_t)row * H + kb;
    float4 u0 = *(const float4*)xr;
    float4 u1 = *(const float4*)(xr + 4);
    half8v a;
    a[0] = (_Float16)u0.x; a[1] = (_Float16)u0.y; a[2] = (_Float16)u0.z; a[3] = (_Float16)u0.w;
    a[4] = (_Float16)u1.x; a[5] = (_Float16)u1.y; a[6] = (_Float16)u1.z; a[7] = (_Float16)u1.w;
#pragma unroll
    for (int ct = 0; ct < 8; ct++) {
      half8v b = PB8[((ct * 4 + ks) * 4 + quad) * 16 + m];
      acc[ct] = __builtin_amdgcn_mfma_f32_16x16x32_f16(a, b, acc[ct], 0, 0, 0);
    }
  }
  float dv[4];
#pragma unroll
  for (int reg = 0; reg < 4; reg++) {
    int ro = r0 + quad * 4 + reg;
    dv[reg] = (ro < n) ? dinv[ro] : 0.f;
  }
#pragma unroll
  for (int ct = 0; ct < 8; ct++) {
#pragma unroll
    for (int reg = 0; reg < 4; reg++) {
      int ro = r0 + quad * 4 + reg;
      if (ro < n) O[(size_t)ro * H + ct * 16 + m] = (_Float16)(acc[ct][reg] * dv[reg]);
    }
  }
}

// Layer-2 GEMM tile: A-load = LN1+ReLU of Xh with precomputed mu/rs; output scaled by dinv.
__device__ __forceinline__ void gemm2_tile(const _Float16* __restrict__ Xh,
                                           const _Float16* __restrict__ PW,
                                           const float* __restrict__ lnw,
                                           const float* __restrict__ lnb,
                                           float mu, float rs,
                                           const float* __restrict__ dinv,
                                           _Float16* __restrict__ O,
                                           int wave, int laneid, int n) {
  int m = laneid & 15;
  int quad = laneid >> 4;
  int r0 = wave * 16;
  int row = r0 + m;
  if (row >= n) row = n - 1;
  floatx4 acc[8] = {};
  const half8v* PB8 = (const half8v*)PW;
#pragma unroll
  for (int ks = 0; ks < 4; ks++) {
    int kb = ks * 32 + quad * 8;
    half8v hv = *(const half8v*)(Xh + (size_t)row * H + kb);
    float4 w0 = *(const float4*)(lnw + kb);
    float4 w1 = *(const float4*)(lnw + kb + 4);
    float4 c0 = *(const float4*)(lnb + kb);
    float4 c1 = *(const float4*)(lnb + kb + 4);
    half8v a;
    a[0] = (_Float16)fmaxf(((float)hv[0] - mu) * rs * w0.x + c0.x, 0.f);
    a[1] = (_Float16)fmaxf(((float)hv[1] - mu) * rs * w0.y + c0.y, 0.f);
    a[2] = (_Float16)fmaxf(((float)hv[2] - mu) * rs * w0.z + c0.z, 0.f);
    a[3] = (_Float16)fmaxf(((float)hv[3] - mu) * rs * w0.w + c0.w, 0.f);
    a[4] = (_Float16)fmaxf(((float)hv[4] - mu) * rs * w1.x + c1.x, 0.f);
    a[5] = (_Float16)fmaxf(((float)hv[5] - mu) * rs * w1.y + c1.y, 0.f);
    a[6] = (_Float16)fmaxf(((float)hv[6] - mu) * rs * w1.z + c1.z, 0.f);
    a[7] = (_Float16)fmaxf(((float)hv[7] - mu) * rs * w1.w + c1.w, 0.f);
#pragma unroll
    for (int ct = 0; ct < 8; ct++) {
      half8v b = PB8[((ct * 4 + ks) * 4 + quad) * 16 + m];
      acc[ct] = __builtin_amdgcn_mfma_f32_16x16x32_f16(a, b, acc[ct], 0, 0, 0);
    }
  }
  float dv[4];
#pragma unroll
  for (int reg = 0; reg < 4; reg++) {
    int ro = r0 + quad * 4 + reg;
    dv[reg] = (ro < n) ? dinv[ro] : 0.f;
  }
#pragma unroll
  for (int ct = 0; ct < 8; ct++) {
#pragma unroll
    for (int reg = 0; reg < 4; reg++) {
      int ro = r0 + quad * 4 + reg;
      if (ro < n) O[(size_t)ro * H + ct * 16 + m] = (_Float16)(acc[ct][reg] * dv[reg]);
    }
  }
}

// One 16-node-group aggregate for node i (16 lanes per node). Accumulates LN
// partials into sv/sq (caller reduces once per block).
__device__ __forceinline__ void agg_group(const _Float16* __restrict__ Gs,
                                          _Float16* __restrict__ Out,
                                          const int* __restrict__ esrc,
                                          const int* __restrict__ offs,
                                          const int* __restrict__ cntE,
                                          const float* __restrict__ dinv,
                                          const float* __restrict__ bias,
                                          int i, int lane, int n,
                                          float& sv, float& sq) {
  if (i >= n) return;
  float di = dinv[i];
  half8v gself = *(const half8v*)&Gs[(size_t)i * H + 8 * lane];
  float acc[8];
#pragma unroll
  for (int e = 0; e < 8; e++) acc[e] = (float)gself[e];
  int beg = offs[i];
  int c16 = (cntE[i] + 15) & ~15;
  int sid = (c16 > 0) ? esrc[beg + lane] : 0;
  for (int base = 0; base < c16; base += 16) {
    int cur = sid;
    if (base + 16 < c16) sid = esrc[beg + base + 16 + lane];
    int sg[16]; half8v hg[16];
#pragma unroll
    for (int u = 0; u < 16; u++) sg[u] = __shfl(cur, u, 16);
#pragma unroll
    for (int u = 0; u < 16; u++) hg[u] = *(const half8v*)&Gs[(size_t)sg[u] * H + 8 * lane];
#pragma unroll
    for (int e = 0; e < 8; e++) {
      float t0 = 0.f, t1 = 0.f;
#pragma unroll
      for (int u = 0; u < 8; u++) { t0 += (float)hg[u][e]; t1 += (float)hg[8 + u][e]; }
      acc[e] += t0 + t1;
    }
  }
  const float* bb = bias + 8 * lane;
  half8v vo;
#pragma unroll
  for (int e = 0; e < 8; e++) {
    float v = di * acc[e] + bb[e];
    vo[e] = (_Float16)v;
    sv += v;
    sq += v * v;
  }
  *(half8v*)&Out[(size_t)i * H + 8 * lane] = vo;
}

// Whole pipeline in one kernel, phases separated by the software grid barrier:
// init-handshake -> 0 init/pack -> 1 count -> 2 alloc -> 3 scatter+gemm1
// -> 4 agg1 -> 5 gemm2 -> 6 agg2 -> 7 pool+fc partials -> 8 sigmoid.
// Phase bodies per-element identical to the verified round-2 kernels.
__global__ __launch_bounds__(256, 2) void k_fused(KParams P) {
  const int tid = threadIdx.x;
  const int bid = blockIdx.x;
  const int nb = gridDim.x;
  const int gtid = bid * 256 + tid;
  const int gstride = nb * 256;
  const int n = P.N, E = P.E, G_ = P.G;
  int* BL = P.bar_leaf; int* BR = P.bar_root; int* BG = P.bar_gen;

  // ---- barrier-state handshake (ws may be POISONED by the harness each iter) ----
  // Block 0 initializes leaf/root/gen iff the magic flag is absent, then
  // publishes the flag; all other blocks wait for the flag before touching
  // anything barrier-related. Idempotent when ws is not re-poisoned (gen is
  // monotonic, leaf/root self-reset), so rocprof replays are safe either way.
  {
    __shared__ int s_need;
    if (bid == 0) {
      if (tid == 0) {
        int f0 = __hip_atomic_load(&P.bar_flag[0], __ATOMIC_RELAXED, __HIP_MEMORY_SCOPE_AGENT);
        int f1 = __hip_atomic_load(&P.bar_flag[1], __ATOMIC_RELAXED, __HIP_MEMORY_SCOPE_AGENT);
        s_need = !(f0 == MAGIC0 && f1 == MAGIC1);
      }
      __syncthreads();
      if (s_need) {
        if (tid < 64) atomicExch(&BL[tid], 0);
        if (tid == 0) { atomicExch(BR, 0); atomicExch(BG, 0); }
      }
      __syncthreads();
      if (tid == 0 && s_need) {
        __threadfence();                       // init lands before flag publish
        atomicExch(&P.bar_flag[0], MAGIC0);
        atomicExch(&P.bar_flag[1], MAGIC1);
      }
    } else {
      if (tid == 0) {
        while (!(__hip_atomic_load(&P.bar_flag[0], __ATOMIC_RELAXED, __HIP_MEMORY_SCOPE_AGENT) == MAGIC0 &&
                 __hip_atomic_load(&P.bar_flag[1], __ATOMIC_RELAXED, __HIP_MEMORY_SCOPE_AGENT) == MAGIC1))
          __builtin_amdgcn_s_sleep(2);
        __threadfence();                       // acquire init
      }
      __syncthreads();
    }
  }

  // ---- phase 0: pack weights + zero state + prefill esrc pads + zero row n ----
  for (int t = gtid; t < 32768; t += gstride) {
    const float* W = (t < 16384) ? P.W1 : P.W2;
    _Float16* PW = (t < 16384) ? P.PW1 : P.PW2;
    int u = t & 16383;
    int j = u & 7;
    int nn = (u >> 3) & 15;
    int quad = (u >> 7) & 3;
    int ks = (u >> 9) & 3;
    int ct = (u >> 11) & 7;
    PW[u] = (_Float16)W[(ks * 32 + quad * 8 + j) * H + ct * 16 + nn];
  }
  for (int j = gtid; j < n; j += gstride) P.cntE[j] = 0;
  for (int j = gtid; j < 256; j += gstride) P.slots[j] = 0.f;
  for (int j = gtid; j < P.CAP; j += gstride) P.esrc[j] = n;
  for (int j = gtid; j < G_; j += gstride) P.glog[j] = 0.f;
  if (gtid == 0) *P.total = 0;
  {
    half8v z = {};
    if (gtid < 16) *(half8v*)&P.bufA[(size_t)n * H + gtid * 8] = z;
    else if (gtid < 32) *(half8v*)&P.bufB[(size_t)n * H + (gtid - 16) * 8] = z;
  }
  gridbar(BL, BR, BG);

  // ---- phase 1: degree count + per-edge slot ----
  for (int e = gtid; e < E; e += gstride) P.perm[e] = atomicAdd(&P.cntE[P.col[e]], 1);
  gridbar(BL, BR, BG);

  // ---- phase 2: 16-aligned segment allocation (block scan + 1 atomic/chunk) ----
  {
    __shared__ int ws[4];
    __shared__ int base_sh;
    int nchunks = (n + 255) >> 8;
    int lane = tid & 63, wid = tid >> 6;
    for (int ch = bid; ch < nchunks; ch += nb) {
      int i = ch * 256 + tid;
      int c = (i < n) ? P.cntE[i] : 0;
      int v = (i < n) ? ((c + 15) & ~15) : 0;
      int incl = v;
#pragma unroll
      for (int o = 1; o < 64; o <<= 1) {
        int t2 = __shfl_up(incl, o, 64);
        if (lane >= o) incl += t2;
      }
      if (lane == 63) ws[wid] = incl;
      __syncthreads();
      if (tid == 0) {
        int s = 0;
#pragma unroll
        for (int w = 0; w < 4; w++) { int t2 = ws[w]; ws[w] = s; s += t2; }
        base_sh = atomicAdd(P.total, s);
      }
      __syncthreads();
      if (i < n) {
        P.offs[i] = base_sh + ws[wid] + (incl - v);
        P.dinv[i] = rsqrtf((float)(c + 1));  // +1 implicit self-loop
      }
      __syncthreads();  // protect ws/base_sh reuse across chunk iterations
    }
  }
  gridbar(BL, BR, BG);

  // ---- phase 3: CSR scatter + gemm1 (g1 = dinv*(x@W1), f16) ----
  for (int e = gtid; e < E; e += gstride) {
    int c = P.col[e];
    P.esrc[P.offs[c] + P.perm[e]] = P.row[e];
  }
  {
    int tiles = (n + 15) >> 4;
    int gw = bid * 4 + (tid >> 6), nw = nb * 4, lane = tid & 63;
    for (int w = gw; w < tiles; w += nw) gemm_tile_f32(P.x, P.PW1, P.dinv, P.bufA, w, lane, n);
  }
  gridbar(BL, BR, BG);

  // ---- phase 4: layer-1 aggregate (bufA -> bufB) + LN1 partials ----
  {
    int ngroups = (n + 15) >> 4;
    int sub = tid >> 4, lane = tid & 15;
    float sv = 0.f, sq = 0.f;
    for (int gr = bid; gr < ngroups; gr += nb)
      agg_group(P.bufA, P.bufB, P.esrc, P.offs, P.cntE, P.dinv, P.b1, gr * 16 + sub, lane, n, sv, sq);
#pragma unroll
    for (int o = 32; o > 0; o >>= 1) { sv += __shfl_xor(sv, o, 64); sq += __shfl_xor(sq, o, 64); }
    __shared__ float rsm1[4], rqm1[4];
    int wid = tid >> 6;
    if ((tid & 63) == 0) { rsm1[wid] = sv; rqm1[wid] = sq; }
    __syncthreads();
    if (tid == 0) {
      atomicAdd(&P.slots[bid & 63], rsm1[0] + rsm1[1] + rsm1[2] + rsm1[3]);
      atomicAdd(&P.slots[64 + (bid & 63)], rqm1[0] + rqm1[1] + rqm1[2] + rqm1[3]);
    }
  }
  gridbar(BL, BR, BG);

  // ---- phase 5: gemm2 with LN1+ReLU fused A-load (bufB -> bufA) ----
  {
    int lane64 = tid & 63;
    float s = P.slots[lane64], q = P.slots[64 + lane64];
#pragma unroll
    for (int o = 32; o > 0; o >>= 1) { s += __shfl_xor(s, o, 64); q += __shfl_xor(q, o, 64); }
    float mu = s * P.invM;
    float var = fmaxf(q * P.invM - mu * mu, 0.f);
    float rs = 1.f / (sqrtf(var) + 1e-5f);
    int tiles = (n + 15) >> 4;
    int gw = bid * 4 + (tid >> 6), nw = nb * 4;
    for (int w = gw; w < tiles; w += nw)
      gemm2_tile(P.bufB, P.PW2, P.ln1w, P.ln1b, mu, rs, P.dinv, P.bufA, w, lane64, n);
  }
  gridbar(BL, BR, BG);

  // ---- phase 6: layer-2 aggregate (bufA -> bufB) + LN2 partials ----
  {
    int ngroups = (n + 15) >> 4;
    int sub = tid >> 4, lane = tid & 15;
    float sv = 0.f, sq = 0.f;
    for (int gr = bid; gr < ngroups; gr += nb)
      agg_group(P.bufA, P.bufB, P.esrc, P.offs, P.cntE, P.dinv, P.b2, gr * 16 + sub, lane, n, sv, sq);
#pragma unroll
    for (int o = 32; o > 0; o >>= 1) { sv += __shfl_xor(sv, o, 64); sq += __shfl_xor(sq, o, 64); }
    __shared__ float rsm2[4], rqm2[4];
    int wid = tid >> 6;
    if ((tid & 63) == 0) { rsm2[wid] = sv; rqm2[wid] = sq; }
    __syncthreads();
    if (tid == 0) {
      atomicAdd(&P.slots[128 + (bid & 63)], rsm2[0] + rsm2[1] + rsm2[2] + rsm2[3]);
      atomicAdd(&P.slots[192 + (bid & 63)], rqm2[0] + rqm2[1] + rqm2[2] + rqm2[3]);
    }
  }
  gridbar(BL, BR, BG);

  // ---- phase 7: LN2+ReLU pool + fc-dot partials into glog ----
  {
    int lane64 = tid & 63;
    float s = P.slots[128 + lane64], q = P.slots[192 + lane64];
#pragma unroll
    for (int o = 32; o > 0; o >>= 1) { s += __shfl_xor(s, o, 64); q += __shfl_xor(q, o, 64); }
    float mu = s * P.invM;
    float var = fmaxf(q * P.invM - mu * mu, 0.f);
    float rs = 1.f / (sqrtf(var) + 1e-5f);

    int half = tid >> 7;      // two 128-thread chunk-units per block
    int t = tid & 127;
    int nch = G_ * PC;
    for (int base = bid * 2; base < nch; base += nb * 2) {
      int c = base + half;
      if (c < nch) {
        int g = c / PC, qch = c % PC;
        int start = lower_bound_i(P.batch, n, g);
        int end = lower_bound_i(P.batch, n, g + 1);
        int tot = end - start;
        int per = (tot + PC - 1) / PC;
        int s0 = start + qch * per;
        int e0 = s0 + per; if (e0 > end) e0 = end;
        float w = P.ln2w[t], bb = P.ln2b[t];
        float acc = 0.f;
        for (int i = s0; i < e0; i++) {
          float v = (float)P.bufB[(size_t)i * H + t];
          v = (v - mu) * rs * w + bb;
          acc += fmaxf(v, 0.f);
        }
        float cnt = fmaxf((float)tot, 1.f);
        float v = acc * P.fcw[t] / cnt;
#pragma unroll
        for (int o = 32; o > 0; o >>= 1) v += __shfl_xor(v, o, 64);
        if ((t & 63) == 0) atomicAdd(&P.glog[g], v);  // one add per wave
      }
    }
  }
  gridbar(BL, BR, BG);

  // ---- phase 8: sigmoid ----
  if (gtid < G_) P.out[gtid] = 1.f / (1.f + expf(-(P.glog[gtid] + P.fcb[0])));
}

extern "C" void kernel_launch(void* const* d_in, const int* in_sizes, int n_in,
                              void* d_out, int out_size, void* d_ws, size_t ws_size,
                              hipStream_t stream) {
  const float* x    = (const float*)d_in[0];
  const int*   ei   = (const int*)d_in[1];
  const int*   batch= (const int*)d_in[2];
  const float* W1   = (const float*)d_in[3];
  const float* b1   = (const float*)d_in[4];
  const float* ln1w = (const float*)d_in[5];
  const float* ln1b = (const float*)d_in[6];
  const float* W2   = (const float*)d_in[7];
  const float* b2   = (const float*)d_in[8];
  const float* ln2w = (const float*)d_in[9];
  const float* ln2b = (const float*)d_in[10];
  const float* fcw  = (const float*)d_in[11];
  const float* fcb  = (const float*)d_in[12];
  float* out = (float*)d_out;

  int N = in_sizes[2];
  int E = in_sizes[1] / 2;
  int G = out_size;
  int CAP = E + 15 * N;   // upper bound on 16-padded edge total

  char* p = (char*)d_ws;
  int*   cntE   = (int*)p;   p += (size_t)N * 4;
  int*   offs   = (int*)p;   p += (size_t)N * 4;
  float* dinv   = (float*)p; p += (size_t)N * 4;
  int*   perm   = (int*)p;   p += (size_t)E * 4;
  int*   esrc   = (int*)p;   p += (size_t)CAP * 4;
  _Float16* bufA = (_Float16*)p; p += (size_t)(N + 1) * H * 2;  // +1 zero-node row
  _Float16* bufB = (_Float16*)p; p += (size_t)(N + 1) * H * 2;
  _Float16* PW1  = (_Float16*)p; p += 16384 * 2;
  _Float16* PW2  = (_Float16*)p; p += 16384 * 2;
  float* slots  = (float*)p; p += 256 * 4;  // [sum1|sq1|sum2|sq2] x64
  float* glog   = (float*)p; p += (size_t)G * 4;
  int*   total  = (int*)p;   p += 4;
  int*   bleaf  = (int*)p;   p += 64 * 4;   // barrier state (poison-tolerant via flag protocol)
  int*   broot  = (int*)p;   p += 4;
  int*   bgen   = (int*)p;   p += 4;
  int*   bflag  = (int*)p;   p += 2 * 4;

  KParams kp;
  kp.x = x; kp.row = ei; kp.col = ei + E; kp.batch = batch;
  kp.W1 = W1; kp.b1 = b1; kp.ln1w = ln1w; kp.ln1b = ln1b;
  kp.W2 = W2; kp.b2 = b2; kp.ln2w = ln2w; kp.ln2b = ln2b;
  kp.fcw = fcw; kp.fcb = fcb;
  kp.out = out;
  kp.cntE = cntE; kp.offs = offs; kp.dinv = dinv; kp.perm = perm; kp.esrc = esrc;
  kp.bufA = bufA; kp.bufB = bufB; kp.PW1 = PW1; kp.PW2 = PW2;
  kp.slots = slots; kp.glog = glog; kp.total = total;
  kp.bar_leaf = bleaf; kp.bar_root = broot; kp.bar_gen = bgen; kp.bar_flag = bflag;
  kp.N = N; kp.E = E; kp.G = G; kp.CAP = CAP;
  kp.invM = 1.f / ((float)N * (float)H);

  k_fused<<<dim3(GRID_BLOCKS), dim3(256), 0, stream>>>(kp);
}

// Round 6
// 260.450 us; speedup vs baseline: 1.8837x; 1.8837x over previous
//
#include <hip/hip_runtime.h>
#include <math.h>

#define H 128
#define PC 16     // pool chunks per graph

typedef _Float16 half8v __attribute__((ext_vector_type(8)));
typedef float floatx4 __attribute__((ext_vector_type(4)));

__device__ __forceinline__ int lower_bound_i(const int* a, int n, int key) {
  int lo = 0, hi = n;
  while (lo < hi) { int mid = (lo + hi) >> 1; if (a[mid] < key) lo = mid + 1; else hi = mid; }
  return lo;
}

// Node-feature buffers use a PLANE layout: 4 planes of 32 dims.
// buf[p*PS + i*32 + d], PS = (N+1)*32 halves. Plane slice = (N+1)*64 B ~= 3.2 MB
// fits a 4 MB per-XCD L2 -> the agg gather becomes L2-resident when each XCD
// works a single plane (blockIdx%8 XCD binding; perf-only assumption).

// blocks 0..127: pack W1/W2 into f16 B-fragment order.
// blocks 128..255: zero cntE, slots; prefill esrc with zero-node id n (16-padding).
// PW[ct*2048 + ks*512 + quad*128 + n*8 + j] = W[(ks*32+quad*8+j)*128 + ct*16+n]
__global__ void k_initpack(const float* __restrict__ W1, const float* __restrict__ W2,
                           _Float16* __restrict__ PW1, _Float16* __restrict__ PW2,
                           int* cntE, float* slots, int* esrc, int cap, int n) {
  int b = blockIdx.x;
  int tid = threadIdx.x;
  if (b < 128) {
    int t = b * 256 + tid;
    const float* W = (t < 16384) ? W1 : W2;
    _Float16* PW = (t < 16384) ? PW1 : PW2;
    int u = t & 16383;
    int j = u & 7;
    int nn = (u >> 3) & 15;
    int quad = (u >> 7) & 3;
    int ks = (u >> 9) & 3;
    int ct = (u >> 11) & 7;
    PW[u] = (_Float16)W[(ks * 32 + quad * 8 + j) * H + ct * 16 + nn];
  } else {
    int i = (b - 128) * 256 + tid;
    int stride = 128 * 256;
    for (int j = i; j < n; j += stride) cntE[j] = 0;
    for (int j = i; j < 256; j += stride) slots[j] = 0.f;
    for (int j = i; j < cap; j += stride) esrc[j] = n;   // pad -> zero-node
  }
}

// count + record per-edge slot (perm) so scatter needs no atomics.
__global__ void k_count(const int* __restrict__ col, int* __restrict__ cntE,
                        int* __restrict__ perm, int E) {
  int e = blockIdx.x * blockDim.x + threadIdx.x;
  if (e < E) perm[e] = atomicAdd(&cntE[col[e]], 1);
}

// exclusive scan over c16 = ceil(cnt/16)*16 (16-aligned segments).
__global__ void k_scan_block(const int* __restrict__ cnt, int* __restrict__ offs,
                             int* __restrict__ bsum, int n) {
  __shared__ int s[256];
  int tid = threadIdx.x;
  int i = blockIdx.x * 256 + tid;
  int v = (i < n) ? ((cnt[i] + 15) & ~15) : 0;
  s[tid] = v;
  __syncthreads();
  for (int d = 1; d < 256; d <<= 1) {
    int t = (tid >= d) ? s[tid - d] : 0;
    __syncthreads();
    s[tid] += t;
    __syncthreads();
  }
  if (i < n) offs[i] = s[tid] - v;           // exclusive
  if (tid == 255) bsum[blockIdx.x] = s[255]; // block total
}

// Adds the top-level scan inline: each block sums bsum[0..blockIdx) itself (NB<=256).
__global__ void k_scan_add(int* __restrict__ offs, const int* __restrict__ bsum,
                           const int* __restrict__ cntE, float* __restrict__ dinv, int n) {
  __shared__ int sh[4];
  int tid = threadIdx.x;
  int v = (tid < blockIdx.x) ? bsum[tid] : 0;
#pragma unroll
  for (int o = 32; o > 0; o >>= 1) v += __shfl_xor(v, o, 64);
  if ((tid & 63) == 0) sh[tid >> 6] = v;
  __syncthreads();
  int boff = sh[0] + sh[1] + sh[2] + sh[3];
  int i = blockIdx.x * 256 + tid;
  if (i < n) {
    offs[i] += boff;
    dinv[i] = rsqrtf((float)(cntE[i] + 1));  // +1 for implicit self-loop
  }
}

// GEMM tile (fp32 input, no LN): writes O[plane layout] = dinv[ro] * (X@W)[ro]  (f16)
__device__ __forceinline__ void gemm_tile_f32(const float* __restrict__ Xf,
                                              const _Float16* __restrict__ PW,
                                              const float* __restrict__ dinv,
                                              _Float16* __restrict__ O, size_t PS,
                                              int wave, int laneid, int n) {
  int m = laneid & 15;
  int quad = laneid >> 4;
  int r0 = wave * 16;
  int row = r0 + m;
  if (row >= n) row = n - 1;
  floatx4 acc[8] = {};
  const half8v* PB8 = (const half8v*)PW;
#pragma unroll
  for (int ks = 0; ks < 4; ks++) {
    int kb = ks * 32 + quad * 8;
    const float* xr = Xf + (size_t)row * H + kb;
    float4 u0 = *(const float4*)xr;
    float4 u1 = *(const float4*)(xr + 4);
    half8v a;
    a[0] = (_Float16)u0.x; a[1] = (_Float16)u0.y; a[2] = (_Float16)u0.z; a[3] = (_Float16)u0.w;
    a[4] = (_Float16)u1.x; a[5] = (_Float16)u1.y; a[6] = (_Float16)u1.z; a[7] = (_Float16)u1.w;
#pragma unroll
    for (int ct = 0; ct < 8; ct++) {
      half8v b = PB8[((ct * 4 + ks) * 4 + quad) * 16 + m];
      acc[ct] = __builtin_amdgcn_mfma_f32_16x16x32_f16(a, b, acc[ct], 0, 0, 0);
    }
  }
  float dv[4];
#pragma unroll
  for (int reg = 0; reg < 4; reg++) {
    int ro = r0 + quad * 4 + reg;
    dv[reg] = (ro < n) ? dinv[ro] : 0.f;
  }
#pragma unroll
  for (int ct = 0; ct < 8; ct++) {
#pragma unroll
    for (int reg = 0; reg < 4; reg++) {
      int ro = r0 + quad * 4 + reg;
      if (ro < n)
        O[(size_t)(ct >> 1) * PS + (size_t)ro * 32 + (ct & 1) * 16 + m] =
            (_Float16)(acc[ct][reg] * dv[reg]);
    }
  }
}

// Fused: blocks [0,GB) run gemm1 (x fp32 -> g1 = dinv*(x@W1)); blocks [GB,..) scatter.
// Block 0 also zeroes the zero-node row n of O in all 4 planes.
__global__ __launch_bounds__(256) void k_sg1(const int* __restrict__ row, const int* __restrict__ col,
                                             const int* __restrict__ offs, const int* __restrict__ perm,
                                             int* __restrict__ esrc, int E,
                                             const float* __restrict__ Xf,
                                             const _Float16* __restrict__ PW,
                                             const float* __restrict__ dinv,
                                             _Float16* __restrict__ O, size_t PS, int n, int GB) {
  int b = blockIdx.x;
  if (b < GB) {
    if (b == 0 && threadIdx.x < 16) {
      half8v z = {};
      int p = threadIdx.x >> 2, seg = threadIdx.x & 3;
      *(half8v*)&O[(size_t)p * PS + (size_t)n * 32 + seg * 8] = z;
    }
    int wave = b * 4 + (threadIdx.x >> 6);
    int tiles = (n + 15) >> 4;
    if (wave >= tiles) return;
    gemm_tile_f32(Xf, PW, dinv, O, PS, wave, threadIdx.x & 63, n);
  } else {
    int e = (b - GB) * 256 + threadIdx.x;
    if (e < E) {
      int c = col[e];
      esrc[offs[c] + perm[e]] = row[e];
    }
  }
}

// Plane-local gather-aggregate. Grid = 8 * ceil(units/2) blocks (units = ceil(n/64));
// plane = (bid>>1)&3 (constant per XCD under bid%8 round-robin), unit = (bid>>3)*2+(bid&1).
// 4 lanes per node cover the 64-B plane row; bursts of 4 edges; 16 nodes per wave.
// Out[plane p] = dinv[i]*(sum g[s] + g[i]) + bias_slice; LN partials -> slot.
__global__ __launch_bounds__(256) void k_agg(const _Float16* __restrict__ Gs,
                                             _Float16* __restrict__ Out,
                                             const int* __restrict__ esrc, const int* __restrict__ offs,
                                             const int* __restrict__ cntE, const float* __restrict__ dinv,
                                             const float* __restrict__ bias, float* __restrict__ slot,
                                             size_t PS, int n) {
  int bid = blockIdx.x;
  int p = (bid >> 1) & 3;
  int u = (bid >> 3) * 2 + (bid & 1);
  int nsub = threadIdx.x >> 2;   // 0..63 node slot within block
  int lane = threadIdx.x & 3;    // 16-B segment within the 64-B plane row
  int i = u * 64 + nsub;
  const _Float16* Gp = Gs + (size_t)p * PS;
  float sv = 0.f, sq = 0.f;
  if (i < n) {
    float di = dinv[i];
    half8v gself = *(const half8v*)&Gp[(size_t)i * 32 + 8 * lane];
    float acc[8];
#pragma unroll
    for (int e = 0; e < 8; e++) acc[e] = (float)gself[e];
    int beg = offs[i];
    int c16 = (cntE[i] + 15) & ~15;
    int sid = (c16 > 0) ? esrc[beg + lane] : 0;
    for (int base = 0; base < c16; base += 4) {
      int cur = sid;
      if (base + 4 < c16) sid = esrc[beg + base + 4 + lane];
      int sg[4]; half8v hg[4];
#pragma unroll
      for (int v = 0; v < 4; v++) sg[v] = __shfl(cur, v, 4);
#pragma unroll
      for (int v = 0; v < 4; v++) hg[v] = *(const half8v*)&Gp[(size_t)sg[v] * 32 + 8 * lane];
#pragma unroll
      for (int e = 0; e < 8; e++)
        acc[e] += ((float)hg[0][e] + (float)hg[1][e]) + ((float)hg[2][e] + (float)hg[3][e]);
    }
    const float* bb = bias + p * 32 + 8 * lane;
    half8v vo;
#pragma unroll
    for (int e = 0; e < 8; e++) {
      float v = di * acc[e] + bb[e];
      vo[e] = (_Float16)v;
      sv += v;
      sq += v * v;
    }
    *(half8v*)&Out[(size_t)p * PS + (size_t)i * 32 + 8 * lane] = vo;
  }
#pragma unroll
  for (int o = 32; o > 0; o >>= 1) {
    sv += __shfl_xor(sv, o, 64);
    sq += __shfl_xor(sq, o, 64);
  }
  __shared__ float rsm[4], rqm[4];
  int wave = threadIdx.x >> 6;
  if ((threadIdx.x & 63) == 0) { rsm[wave] = sv; rqm[wave] = sq; }
  __syncthreads();
  if (threadIdx.x == 0) {
    float ts = rsm[0] + rsm[1] + rsm[2] + rsm[3];
    float tq = rqm[0] + rqm[1] + rqm[2] + rqm[3];
    int sl = blockIdx.x & 63;
    atomicAdd(&slot[sl], ts);
    atomicAdd(&slot[64 + sl], tq);
  }
}

// Layer-2 GEMM: A-load = LN1+ReLU of Xh (plane layout; mu/rstd from slot butterfly),
// output scaled by dinv, written in plane layout. Block 0 zeroes row n (all planes).
__global__ __launch_bounds__(256) void k_gemm2(const _Float16* __restrict__ Xh,
                                               const _Float16* __restrict__ PW,
                                               const float* __restrict__ lnw,
                                               const float* __restrict__ lnb,
                                               const float* __restrict__ slot, float invM,
                                               const float* __restrict__ dinv,
                                               _Float16* __restrict__ O, size_t PS, int n) {
  if (blockIdx.x == 0 && threadIdx.x < 16) {
    half8v z = {};
    int p = threadIdx.x >> 2, seg = threadIdx.x & 3;
    *(half8v*)&O[(size_t)p * PS + (size_t)n * 32 + seg * 8] = z;
  }
  int wave = blockIdx.x * 4 + (threadIdx.x >> 6);
  int tiles = (n + 15) >> 4;
  if (wave >= tiles) return;
  int lane = threadIdx.x & 63;
  int m = lane & 15;
  int quad = lane >> 4;
  int r0 = wave * 16;
  int row = r0 + m;
  if (row >= n) row = n - 1;

  float s = slot[lane], q = slot[64 + lane];
#pragma unroll
  for (int o = 32; o > 0; o >>= 1) { s += __shfl_xor(s, o, 64); q += __shfl_xor(q, o, 64); }
  float mu = s * invM;
  float var = fmaxf(q * invM - mu * mu, 0.f);
  float rs = 1.f / (sqrtf(var) + 1e-5f);

  floatx4 acc[8] = {};
  const half8v* PB8 = (const half8v*)PW;
#pragma unroll
  for (int ks = 0; ks < 4; ks++) {
    int kb = ks * 32 + quad * 8;
    half8v hv = *(const half8v*)(Xh + (size_t)ks * PS + (size_t)row * 32 + quad * 8);
    float4 w0 = *(const float4*)(lnw + kb);
    float4 w1 = *(const float4*)(lnw + kb + 4);
    float4 c0 = *(const float4*)(lnb + kb);
    float4 c1 = *(const float4*)(lnb + kb + 4);
    half8v a;
    a[0] = (_Float16)fmaxf(((float)hv[0] - mu) * rs * w0.x + c0.x, 0.f);
    a[1] = (_Float16)fmaxf(((float)hv[1] - mu) * rs * w0.y + c0.y, 0.f);
    a[2] = (_Float16)fmaxf(((float)hv[2] - mu) * rs * w0.z + c0.z, 0.f);
    a[3] = (_Float16)fmaxf(((float)hv[3] - mu) * rs * w0.w + c0.w, 0.f);
    a[4] = (_Float16)fmaxf(((float)hv[4] - mu) * rs * w1.x + c1.x, 0.f);
    a[5] = (_Float16)fmaxf(((float)hv[5] - mu) * rs * w1.y + c1.y, 0.f);
    a[6] = (_Float16)fmaxf(((float)hv[6] - mu) * rs * w1.z + c1.z, 0.f);
    a[7] = (_Float16)fmaxf(((float)hv[7] - mu) * rs * w1.w + c1.w, 0.f);
#pragma unroll
    for (int ct = 0; ct < 8; ct++) {
      half8v b = PB8[((ct * 4 + ks) * 4 + quad) * 16 + m];
      acc[ct] = __builtin_amdgcn_mfma_f32_16x16x32_f16(a, b, acc[ct], 0, 0, 0);
    }
  }
  float dv[4];
#pragma unroll
  for (int reg = 0; reg < 4; reg++) {
    int ro = r0 + quad * 4 + reg;
    dv[reg] = (ro < n) ? dinv[ro] : 0.f;
  }
#pragma unroll
  for (int ct = 0; ct < 8; ct++) {
#pragma unroll
    for (int reg = 0; reg < 4; reg++) {
      int ro = r0 + quad * 4 + reg;
      if (ro < n)
        O[(size_t)(ct >> 1) * PS + (size_t)ro * 32 + (ct & 1) * 16 + m] =
            (_Float16)(acc[ct][reg] * dv[reg]);
    }
  }
}

// LN2+ReLU fused pooling: PC blocks per graph, private psum slot per block
// (unconditional store -> no init, no atomics, deterministic). Plane-layout reads.
__global__ __launch_bounds__(128) void k_pool(const _Float16* __restrict__ Hs,
                                              const int* __restrict__ batch,
                                              const float* __restrict__ lnw, const float* __restrict__ lnb,
                                              const float* __restrict__ slot, float invM,
                                              float* __restrict__ psum, size_t PS, int n) {
  int g = blockIdx.x / PC, q = blockIdx.x % PC;
  int t = threadIdx.x;
  int l = t & 63;
  float s = slot[l], qq = slot[64 + l];
#pragma unroll
  for (int o = 32; o > 0; o >>= 1) { s += __shfl_xor(s, o, 64); qq += __shfl_xor(qq, o, 64); }
  float mu = s * invM;
  float var = fmaxf(qq * invM - mu * mu, 0.f);
  float rs = 1.f / (sqrtf(var) + 1e-5f);

  int start = lower_bound_i(batch, n, g);
  int end = lower_bound_i(batch, n, g + 1);
  int tot = end - start;
  int per = (tot + PC - 1) / PC;
  int s0 = start + q * per;
  int e0 = s0 + per; if (e0 > end) e0 = end;
  float w = lnw[t], bb = lnb[t];
  const _Float16* Hp = Hs + (size_t)(t >> 5) * PS + (t & 31);
  float acc = 0.f;
  for (int i = s0; i < e0; i++) {
    float v = (float)Hp[(size_t)i * 32];
    v = (v - mu) * rs * w + bb;
    acc += fmaxf(v, 0.f);
  }
  psum[(size_t)blockIdx.x * H + t] = acc;   // unconditional store: no init needed
}

__global__ __launch_bounds__(128) void k_fc(const float* __restrict__ psum, const int* __restrict__ batch,
                                            const float* __restrict__ fcw, const float* __restrict__ fcb,
                                            float* __restrict__ out, int n) {
  int g = blockIdx.x;
  int t = threadIdx.x;
  int start = lower_bound_i(batch, n, g);
  int end = lower_bound_i(batch, n, g + 1);
  float cnt = fmaxf((float)(end - start), 1.f);
  float tot = 0.f;
#pragma unroll
  for (int c = 0; c < PC; c++) tot += psum[(size_t)(g * PC + c) * H + t];
  float v = tot / cnt * fcw[t];
  int lane = t & 63, wave = t >> 6;
#pragma unroll
  for (int o = 32; o > 0; o >>= 1) v += __shfl_xor(v, o, 64);
  __shared__ float r2[2];
  if (lane == 0) r2[wave] = v;
  __syncthreads();
  if (t == 0) {
    float logit = r2[0] + r2[1] + fcb[0];
    out[g] = 1.f / (1.f + expf(-logit));
  }
}

extern "C" void kernel_launch(void* const* d_in, const int* in_sizes, int n_in,
                              void* d_out, int out_size, void* d_ws, size_t ws_size,
                              hipStream_t stream) {
  const float* x    = (const float*)d_in[0];
  const int*   ei   = (const int*)d_in[1];
  const int*   batch= (const int*)d_in[2];
  const float* W1   = (const float*)d_in[3];
  const float* b1   = (const float*)d_in[4];
  const float* ln1w = (const float*)d_in[5];
  const float* ln1b = (const float*)d_in[6];
  const float* W2   = (const float*)d_in[7];
  const float* b2   = (const float*)d_in[8];
  const float* ln2w = (const float*)d_in[9];
  const float* ln2b = (const float*)d_in[10];
  const float* fcw  = (const float*)d_in[11];
  const float* fcb  = (const float*)d_in[12];
  float* out = (float*)d_out;

  int N = in_sizes[2];
  int E = in_sizes[1] / 2;
  int G = out_size;
  int CAP = E + 15 * N;            // upper bound on 16-padded edge total
  size_t PS = (size_t)(N + 1) * 32;  // halves per plane (4 planes per buffer)

  char* p = (char*)d_ws;
  int*   cntE   = (int*)p;   p += (size_t)N * 4;
  int*   offs   = (int*)p;   p += (size_t)N * 4;
  float* dinv   = (float*)p; p += (size_t)N * 4;
  int*   perm   = (int*)p;   p += (size_t)E * 4;
  int*   esrc   = (int*)p;   p += (size_t)CAP * 4;
  _Float16* bufA = (_Float16*)p; p += (size_t)(N + 1) * H * 2;  // 4 planes incl. zero-node row
  _Float16* bufB = (_Float16*)p; p += (size_t)(N + 1) * H * 2;
  _Float16* PW1  = (_Float16*)p; p += 16384 * 2;
  _Float16* PW2  = (_Float16*)p; p += 16384 * 2;
  float* slots  = (float*)p; p += 256 * 4;  // [sum1|sq1|sum2|sq2] x64
  int*   bsum   = (int*)p;   p += 256 * 4;
  float* psum   = (float*)p; p += (size_t)G * PC * H * 4;

  const int* row = ei;
  const int* col = ei + E;

  k_initpack<<<256, 256, 0, stream>>>(W1, W2, PW1, PW2, cntE, slots, esrc, CAP, N);
  int EB = (E + 255) / 256;
  k_count<<<EB, 256, 0, stream>>>(col, cntE, perm, E);
  int NB = (N + 255) / 256;
  k_scan_block<<<NB, 256, 0, stream>>>(cntE, offs, bsum, N);
  k_scan_add<<<NB, 256, 0, stream>>>(offs, bsum, cntE, dinv, N);

  int tiles = (N + 15) / 16;
  int GB = (tiles + 3) / 4;
  float invM = 1.f / ((float)N * (float)H);

  // plane-agg grid: units = ceil(N/64) node-groups; 8 blocks per 2 units (4 planes x 2 XCDs)
  int units = (N + 63) / 64;
  int AGB = 8 * ((units + 1) / 2);

  // scatter + gemm1 fused (gemm1 writes g1 = dinv * (x@W1) in f16 plane layout)
  k_sg1<<<GB + EB, 256, 0, stream>>>(row, col, offs, perm, esrc, E, x, PW1, dinv, bufA, PS, N, GB);
  k_agg<<<AGB, 256, 0, stream>>>(bufA, bufB, esrc, offs, cntE, dinv, b1, slots, PS, N);
  // layer 2 (LN1+ReLU fused into gemm A-load; scal from slots; output pre-scaled)
  k_gemm2<<<GB, 256, 0, stream>>>(bufB, PW2, ln1w, ln1b, slots, invM, dinv, bufA, PS, N);
  k_agg<<<AGB, 256, 0, stream>>>(bufA, bufB, esrc, offs, cntE, dinv, b2, slots + 128, PS, N);
  // pool (LN2+ReLU fused, scal inline, deterministic) + fc + sigmoid
  k_pool<<<G * PC, 128, 0, stream>>>(bufB, batch, ln2w, ln2b, slots + 128, invM, psum, PS, N);
  k_fc<<<G, 128, 0, stream>>>(psum, batch, fcw, fcb, out, N);
}

// Round 8
// 246.596 us; speedup vs baseline: 1.9896x; 1.0562x over previous
//
#include <hip/hip_runtime.h>
#include <math.h>

#define H 128
#define PC 16     // pool chunks per graph

typedef _Float16 half8v __attribute__((ext_vector_type(8)));
typedef float floatx4 __attribute__((ext_vector_type(4)));

__device__ __forceinline__ int lower_bound_i(const int* a, int n, int key) {
  int lo = 0, hi = n;
  while (lo < hi) { int mid = (lo + hi) >> 1; if (a[mid] < key) lo = mid + 1; else hi = mid; }
  return lo;
}

// blocks 0..127: pack W1/W2 into f16 B-fragment order.
// blocks 128..255: zero cntE, slots; prefill esrc with zero-node id n (16-padding).
// PW[ct*2048 + ks*512 + quad*128 + n*8 + j] = W[(ks*32+quad*8+j)*128 + ct*16+n]
__global__ void k_initpack(const float* __restrict__ W1, const float* __restrict__ W2,
                           _Float16* __restrict__ PW1, _Float16* __restrict__ PW2,
                           int* cntE, float* slots, int* esrc, int cap, int n) {
  int b = blockIdx.x;
  int tid = threadIdx.x;
  if (b < 128) {
    int t = b * 256 + tid;
    const float* W = (t < 16384) ? W1 : W2;
    _Float16* PW = (t < 16384) ? PW1 : PW2;
    int u = t & 16383;
    int j = u & 7;
    int nn = (u >> 3) & 15;
    int quad = (u >> 7) & 3;
    int ks = (u >> 9) & 3;
    int ct = (u >> 11) & 7;
    PW[u] = (_Float16)W[(ks * 32 + quad * 8 + j) * H + ct * 16 + nn];
  } else {
    int i = (b - 128) * 256 + tid;
    int stride = 128 * 256;
    for (int j = i; j < n; j += stride) cntE[j] = 0;
    for (int j = i; j < 256; j += stride) slots[j] = 0.f;
    for (int j = i; j < cap; j += stride) esrc[j] = n;   // pad -> zero-node
  }
}

// count + record per-edge slot (perm) so scatter needs no atomics.
__global__ void k_count(const int* __restrict__ col, int* __restrict__ cntE,
                        int* __restrict__ perm, int E) {
  int e = blockIdx.x * blockDim.x + threadIdx.x;
  if (e < E) perm[e] = atomicAdd(&cntE[col[e]], 1);
}

// exclusive scan over c16 = ceil(cnt/16)*16 (16-aligned segments).
__global__ void k_scan_block(const int* __restrict__ cnt, int* __restrict__ offs,
                             int* __restrict__ bsum, int n) {
  __shared__ int s[256];
  int tid = threadIdx.x;
  int i = blockIdx.x * 256 + tid;
  int v = (i < n) ? ((cnt[i] + 15) & ~15) : 0;
  s[tid] = v;
  __syncthreads();
  for (int d = 1; d < 256; d <<= 1) {
    int t = (tid >= d) ? s[tid - d] : 0;
    __syncthreads();
    s[tid] += t;
    __syncthreads();
  }
  if (i < n) offs[i] = s[tid] - v;           // exclusive
  if (tid == 255) bsum[blockIdx.x] = s[255]; // block total
}

// Adds the top-level scan inline: each block sums bsum[0..blockIdx) itself (NB<=256).
__global__ void k_scan_add(int* __restrict__ offs, const int* __restrict__ bsum,
                           const int* __restrict__ cntE, float* __restrict__ dinv, int n) {
  __shared__ int sh[4];
  int tid = threadIdx.x;
  int v = (tid < blockIdx.x) ? bsum[tid] : 0;
#pragma unroll
  for (int o = 32; o > 0; o >>= 1) v += __shfl_xor(v, o, 64);
  if ((tid & 63) == 0) sh[tid >> 6] = v;
  __syncthreads();
  int boff = sh[0] + sh[1] + sh[2] + sh[3];
  int i = blockIdx.x * 256 + tid;
  if (i < n) {
    offs[i] += boff;
    dinv[i] = rsqrtf((float)(cntE[i] + 1));  // +1 for implicit self-loop
  }
}

// GEMM tile (fp32 input, no LN): O[ro] = dinv[ro] * (X@W)[ro]  (f16).
// Epilogue staged through LDS (stw: 16 rows x 132-half padded stride) so global
// stores are fully-coalesced 256-B row segments per 16 lanes (1 KB per wave
// instruction) instead of 4x scattered 32-B chunks (2.3x write amplification,
// round-1 PMC). Intra-wave LDS write->read: compiler inserts lgkmcnt waits;
// only same-wave lanes exchange -> no barrier needed.
__device__ __forceinline__ void gemm_tile_f32(const float* __restrict__ Xf,
                                              const _Float16* __restrict__ PW,
                                              const float* __restrict__ dinv,
                                              _Float16* __restrict__ O,
                                              _Float16 (* __restrict__ stw)[132],
                                              int wave, int laneid, int n) {
  int m = laneid & 15;
  int quad = laneid >> 4;
  int r0 = wave * 16;
  int row = r0 + m;
  if (row >= n) row = n - 1;
  floatx4 acc[8] = {};
  const half8v* PB8 = (const half8v*)PW;
#pragma unroll
  for (int ks = 0; ks < 4; ks++) {
    int kb = ks * 32 + quad * 8;
    const float* xr = Xf + (size_t)row * H + kb;
    float4 u0 = *(const float4*)xr;
    float4 u1 = *(const float4*)(xr + 4);
    half8v a;
    a[0] = (_Float16)u0.x; a[1] = (_Float16)u0.y; a[2] = (_Float16)u0.z; a[3] = (_Float16)u0.w;
    a[4] = (_Float16)u1.x; a[5] = (_Float16)u1.y; a[6] = (_Float16)u1.z; a[7] = (_Float16)u1.w;
#pragma unroll
    for (int ct = 0; ct < 8; ct++) {
      half8v b = PB8[((ct * 4 + ks) * 4 + quad) * 16 + m];
      acc[ct] = __builtin_amdgcn_mfma_f32_16x16x32_f16(a, b, acc[ct], 0, 0, 0);
    }
  }
  float dv[4];
#pragma unroll
  for (int reg = 0; reg < 4; reg++) {
    int ro = r0 + quad * 4 + reg;
    dv[reg] = (ro < n) ? dinv[ro] : 0.f;
  }
#pragma unroll
  for (int ct = 0; ct < 8; ct++)
#pragma unroll
    for (int reg = 0; reg < 4; reg++)
      stw[quad * 4 + reg][ct * 16 + m] = (_Float16)(acc[ct][reg] * dv[reg]);
#pragma unroll
  for (int pass = 0; pass < 4; pass++) {
    int chunk = pass * 64 + laneid;
    int rrow = chunk >> 4, cc = chunk & 15;
    half8v vv = *(const half8v*)&stw[rrow][cc * 8];
    int ro = r0 + rrow;
    if (ro < n) *(half8v*)&O[(size_t)ro * H + cc * 8] = vv;
  }
}

// Fused: blocks [0,GB) run gemm1 (x fp32 -> g1 = dinv*(x@W1)); blocks [GB,..) scatter.
// Block 0 also zeroes the zero-node row n of O.
__global__ __launch_bounds__(256) void k_sg1(const int* __restrict__ row, const int* __restrict__ col,
                                             const int* __restrict__ offs, const int* __restrict__ perm,
                                             int* __restrict__ esrc, int E,
                                             const float* __restrict__ Xf,
                                             const _Float16* __restrict__ PW,
                                             const float* __restrict__ dinv,
                                             _Float16* __restrict__ O, int n, int GB) {
  __shared__ _Float16 st[4][16][132];
  int b = blockIdx.x;
  if (b < GB) {
    if (b == 0 && threadIdx.x < 16) {
      half8v z = {};
      *(half8v*)&O[(size_t)n * H + threadIdx.x * 8] = z;
    }
    int wid = threadIdx.x >> 6;
    int wave = b * 4 + wid;
    int tiles = (n + 15) >> 4;
    if (wave >= tiles) return;
    gemm_tile_f32(Xf, PW, dinv, O, st[wid], wave, threadIdx.x & 63, n);
  } else {
    int e = (b - GB) * 256 + threadIdx.x;
    if (e < E) {
      int c = col[e];
      esrc[offs[c] + perm[e]] = row[e];
    }
  }
}

// Gs holds g = dinv*h (pre-scaled rows; row n = 0). Edge lists 16-padded with n.
// Out[i] = dinv[i]*(sum g[s] + g[i]) + bias. Uniform full-16 bursts, sid prefetch.
// LN partial sums -> slot[0..63], slot[64..127].
__global__ __launch_bounds__(256) void k_agg(const _Float16* __restrict__ Gs,
                                             _Float16* __restrict__ Out,
                                             const int* __restrict__ esrc, const int* __restrict__ offs,
                                             const int* __restrict__ cntE, const float* __restrict__ dinv,
                                             const float* __restrict__ bias, float* __restrict__ slot,
                                             int n) {
  int sub = threadIdx.x >> 4;   // 0..15 node slot within block
  int lane = threadIdx.x & 15;
  int i = blockIdx.x * 16 + sub;
  float sv = 0.f, sq = 0.f;
  if (i < n) {
    float di = dinv[i];
    half8v gself = *(const half8v*)&Gs[(size_t)i * H + 8 * lane];
    float acc[8];
#pragma unroll
    for (int e = 0; e < 8; e++) acc[e] = (float)gself[e];
    int beg = offs[i];
    int c16 = (cntE[i] + 15) & ~15;
    int sid = (c16 > 0) ? esrc[beg + lane] : 0;
    for (int base = 0; base < c16; base += 16) {
      int cur = sid;
      if (base + 16 < c16) sid = esrc[beg + base + 16 + lane];
      int sg[16]; half8v hg[16];
#pragma unroll
      for (int u = 0; u < 16; u++) sg[u] = __shfl(cur, u, 16);
#pragma unroll
      for (int u = 0; u < 16; u++) hg[u] = *(const half8v*)&Gs[(size_t)sg[u] * H + 8 * lane];
#pragma unroll
      for (int e = 0; e < 8; e++) {
        float t0 = 0.f, t1 = 0.f;
#pragma unroll
        for (int u = 0; u < 8; u++) { t0 += (float)hg[u][e]; t1 += (float)hg[8 + u][e]; }
        acc[e] += t0 + t1;
      }
    }
    const float* bb = bias + 8 * lane;
    half8v vo;
#pragma unroll
    for (int e = 0; e < 8; e++) {
      float v = di * acc[e] + bb[e];
      vo[e] = (_Float16)v;
      sv += v;
      sq += v * v;
    }
    *(half8v*)&Out[(size_t)i * H + 8 * lane] = vo;
  }
#pragma unroll
  for (int o = 32; o > 0; o >>= 1) {
    sv += __shfl_xor(sv, o, 64);
    sq += __shfl_xor(sq, o, 64);
  }
  __shared__ float rsm[4], rqm[4];
  int wave = threadIdx.x >> 6;
  if ((threadIdx.x & 63) == 0) { rsm[wave] = sv; rqm[wave] = sq; }
  __syncthreads();
  if (threadIdx.x == 0) {
    float ts = rsm[0] + rsm[1] + rsm[2] + rsm[3];
    float tq = rqm[0] + rqm[1] + rqm[2] + rqm[3];
    int sl = blockIdx.x & 63;
    atomicAdd(&slot[sl], ts);
    atomicAdd(&slot[64 + sl], tq);
  }
}

// Layer-2 GEMM: A-load = LN1+ReLU of Xh (mu/rstd from slot butterfly), output scaled
// by dinv. LDS-staged coalesced epilogue (same as gemm1). Block 0 zeroes row n of O.
__global__ __launch_bounds__(256) void k_gemm2(const _Float16* __restrict__ Xh,
                                               const _Float16* __restrict__ PW,
                                               const float* __restrict__ lnw,
                                               const float* __restrict__ lnb,
                                               const float* __restrict__ slot, float invM,
                                               const float* __restrict__ dinv,
                                               _Float16* __restrict__ O, int n) {
  __shared__ _Float16 st[4][16][132];
  if (blockIdx.x == 0 && threadIdx.x < 16) {
    half8v z = {};
    *(half8v*)&O[(size_t)n * H + threadIdx.x * 8] = z;
  }
  int wid = threadIdx.x >> 6;
  int wave = blockIdx.x * 4 + wid;
  int tiles = (n + 15) >> 4;
  if (wave >= tiles) return;
  int laneid = threadIdx.x & 63;
  int m = laneid & 15;
  int quad = laneid >> 4;
  int r0 = wave * 16;
  int row = r0 + m;
  if (row >= n) row = n - 1;

  float s = slot[laneid], q = slot[64 + laneid];
#pragma unroll
  for (int o = 32; o > 0; o >>= 1) { s += __shfl_xor(s, o, 64); q += __shfl_xor(q, o, 64); }
  float mu = s * invM;
  float var = fmaxf(q * invM - mu * mu, 0.f);
  float rs = 1.f / (sqrtf(var) + 1e-5f);

  floatx4 acc[8] = {};
  const half8v* PB8 = (const half8v*)PW;
#pragma unroll
  for (int ks = 0; ks < 4; ks++) {
    int kb = ks * 32 + quad * 8;
    half8v hv = *(const half8v*)(Xh + (size_t)row * H + kb);
    float4 w0 = *(const float4*)(lnw + kb);
    float4 w1 = *(const float4*)(lnw + kb + 4);
    float4 c0 = *(const float4*)(lnb + kb);
    float4 c1 = *(const float4*)(lnb + kb + 4);
    half8v a;
    a[0] = (_Float16)fmaxf(((float)hv[0] - mu) * rs * w0.x + c0.x, 0.f);
    a[1] = (_Float16)fmaxf(((float)hv[1] - mu) * rs * w0.y + c0.y, 0.f);
    a[2] = (_Float16)fmaxf(((float)hv[2] - mu) * rs * w0.z + c0.z, 0.f);
    a[3] = (_Float16)fmaxf(((float)hv[3] - mu) * rs * w0.w + c0.w, 0.f);
    a[4] = (_Float16)fmaxf(((float)hv[4] - mu) * rs * w1.x + c1.x, 0.f);
    a[5] = (_Float16)fmaxf(((float)hv[5] - mu) * rs * w1.y + c1.y, 0.f);
    a[6] = (_Float16)fmaxf(((float)hv[6] - mu) * rs * w1.z + c1.z, 0.f);
    a[7] = (_Float16)fmaxf(((float)hv[7] - mu) * rs * w1.w + c1.w, 0.f);
#pragma unroll
    for (int ct = 0; ct < 8; ct++) {
      half8v b = PB8[((ct * 4 + ks) * 4 + quad) * 16 + m];
      acc[ct] = __builtin_amdgcn_mfma_f32_16x16x32_f16(a, b, acc[ct], 0, 0, 0);
    }
  }
  float dv[4];
#pragma unroll
  for (int reg = 0; reg < 4; reg++) {
    int ro = r0 + quad * 4 + reg;
    dv[reg] = (ro < n) ? dinv[ro] : 0.f;
  }
#pragma unroll
  for (int ct = 0; ct < 8; ct++)
#pragma unroll
    for (int reg = 0; reg < 4; reg++)
      st[wid][quad * 4 + reg][ct * 16 + m] = (_Float16)(acc[ct][reg] * dv[reg]);
#pragma unroll
  for (int pass = 0; pass < 4; pass++) {
    int chunk = pass * 64 + laneid;
    int rrow = chunk >> 4, cc = chunk & 15;
    half8v vv = *(const half8v*)&st[wid][rrow][cc * 8];
    int ro = r0 + rrow;
    if (ro < n) *(half8v*)&O[(size_t)ro * H + cc * 8] = vv;
  }
}

// LN2+ReLU fused pooling: PC blocks per graph, private slot per block
// (unconditional store -> no init, no atomics, deterministic).
__global__ __launch_bounds__(128) void k_pool(const _Float16* __restrict__ Hs,
                                              const int* __restrict__ batch,
                                              const float* __restrict__ lnw, const float* __restrict__ lnb,
                                              const float* __restrict__ slot, float invM,
                                              float* __restrict__ psum, int n) {
  int g = blockIdx.x / PC, q = blockIdx.x % PC;
  int t = threadIdx.x;
  int l = t & 63;
  float s = slot[l], qq = slot[64 + l];
#pragma unroll
  for (int o = 32; o > 0; o >>= 1) { s += __shfl_xor(s, o, 64); qq += __shfl_xor(qq, o, 64); }
  float mu = s * invM;
  float var = fmaxf(qq * invM - mu * mu, 0.f);
  float rs = 1.f / (sqrtf(var) + 1e-5f);

  int start = lower_bound_i(batch, n, g);
  int end = lower_bound_i(batch, n, g + 1);
  int tot = end - start;
  int per = (tot + PC - 1) / PC;
  int s0 = start + q * per;
  int e0 = s0 + per; if (e0 > end) e0 = end;
  float w = lnw[t], bb = lnb[t];
  float acc = 0.f;
  for (int i = s0; i < e0; i++) {
    float v = (float)Hs[(size_t)i * H + t];
    v = (v - mu) * rs * w + bb;
    acc += fmaxf(v, 0.f);
  }
  psum[(size_t)blockIdx.x * H + t] = acc;   // unconditional store: no init needed
}

__global__ __launch_bounds__(128) void k_fc(const float* __restrict__ psum, const int* __restrict__ batch,
                                            const float* __restrict__ fcw, const float* __restrict__ fcb,
                                            float* __restrict__ out, int n) {
  int g = blockIdx.x;
  int t = threadIdx.x;
  int start = lower_bound_i(batch, n, g);
  int end = lower_bound_i(batch, n, g + 1);
  float cnt = fmaxf((float)(end - start), 1.f);
  float tot = 0.f;
#pragma unroll
  for (int c = 0; c < PC; c++) tot += psum[(size_t)(g * PC + c) * H + t];
  float v = tot / cnt * fcw[t];
  int lane = t & 63, wave = t >> 6;
#pragma unroll
  for (int o = 32; o > 0; o >>= 1) v += __shfl_xor(v, o, 64);
  __shared__ float r2[2];
  if (lane == 0) r2[wave] = v;
  __syncthreads();
  if (t == 0) {
    float logit = r2[0] + r2[1] + fcb[0];
    out[g] = 1.f / (1.f + expf(-logit));
  }
}

extern "C" void kernel_launch(void* const* d_in, const int* in_sizes, int n_in,
                              void* d_out, int out_size, void* d_ws, size_t ws_size,
                              hipStream_t stream) {
  const float* x    = (const float*)d_in[0];
  const int*   ei   = (const int*)d_in[1];
  const int*   batch= (const int*)d_in[2];
  const float* W1   = (const float*)d_in[3];
  const float* b1   = (const float*)d_in[4];
  const float* ln1w = (const float*)d_in[5];
  const float* ln1b = (const float*)d_in[6];
  const float* W2   = (const float*)d_in[7];
  const float* b2   = (const float*)d_in[8];
  const float* ln2w = (const float*)d_in[9];
  const float* ln2b = (const float*)d_in[10];
  const float* fcw  = (const float*)d_in[11];
  const float* fcb  = (const float*)d_in[12];
  float* out = (float*)d_out;

  int N = in_sizes[2];
  int E = in_sizes[1] / 2;
  int G = out_size;
  int CAP = E + 15 * N;   // upper bound on 16-padded edge total

  char* p = (char*)d_ws;
  int*   cntE   = (int*)p;   p += (size_t)N * 4;
  int*   offs   = (int*)p;   p += (size_t)N * 4;
  float* dinv   = (float*)p; p += (size_t)N * 4;
  int*   perm   = (int*)p;   p += (size_t)E * 4;
  int*   esrc   = (int*)p;   p += (size_t)CAP * 4;
  _Float16* bufA = (_Float16*)p; p += (size_t)(N + 1) * H * 2;  // +1 zero-node row
  _Float16* bufB = (_Float16*)p; p += (size_t)(N + 1) * H * 2;
  _Float16* PW1  = (_Float16*)p; p += 16384 * 2;
  _Float16* PW2  = (_Float16*)p; p += 16384 * 2;
  float* slots  = (float*)p; p += 256 * 4;  // [sum1|sq1|sum2|sq2] x64
  int*   bsum   = (int*)p;   p += 256 * 4;
  float* psum   = (float*)p; p += (size_t)G * PC * H * 4;

  const int* row = ei;
  const int* col = ei + E;

  k_initpack<<<256, 256, 0, stream>>>(W1, W2, PW1, PW2, cntE, slots, esrc, CAP, N);
  int EB = (E + 255) / 256;
  k_count<<<EB, 256, 0, stream>>>(col, cntE, perm, E);
  int NB = (N + 255) / 256;
  k_scan_block<<<NB, 256, 0, stream>>>(cntE, offs, bsum, N);
  k_scan_add<<<NB, 256, 0, stream>>>(offs, bsum, cntE, dinv, N);

  int tiles = (N + 15) / 16;
  int GB = (tiles + 3) / 4;
  float invM = 1.f / ((float)N * (float)H);

  // scatter + gemm1 fused (coalesced LDS epilogue; zero-node row cleared)
  k_sg1<<<GB + EB, 256, 0, stream>>>(row, col, offs, perm, esrc, E, x, PW1, dinv, bufA, N, GB);
  // layer-1 aggregate, + b1, LN1 partials
  k_agg<<<(N + 15) / 16, 256, 0, stream>>>(bufA, bufB, esrc, offs, cntE, dinv, b1, slots, N);
  // layer 2 (LN1+ReLU fused into gemm A-load; coalesced LDS epilogue)
  k_gemm2<<<GB, 256, 0, stream>>>(bufB, PW2, ln1w, ln1b, slots, invM, dinv, bufA, N);
  // layer-2 aggregate, + b2, LN2 partials
  k_agg<<<(N + 15) / 16, 256, 0, stream>>>(bufA, bufB, esrc, offs, cntE, dinv, b2, slots + 128, N);
  // pool (LN2+ReLU fused, deterministic) + fc + sigmoid
  k_pool<<<G * PC, 128, 0, stream>>>(bufB, batch, ln2w, ln2b, slots + 128, invM, psum, N);
  k_fc<<<G, 128, 0, stream>>>(psum, batch, fcw, fcb, out, N);
}